// Round 2
// baseline (366.097 us; speedup 1.0000x reference)
//
#include <hip/hip_runtime.h>

// PILayer: out = tanh((prop[idx_i] + basis + prop[idx_j]) @ W1 + b1) @ W2 + b2
// E=320000, D_IN=128, D_HID=256, D_OUT=128. fp32 in/out, fp16 MFMA internally.
//
// Persistent 512-block grid, grid-stride over 5000 tiles, double-buffered sA
// staging pipelined across tiles (T14 split: idx+basis at top, prop gathers
// after GEMM1, commit after GEMM2), raw s_barrier with lgkmcnt-only waits so
// prefetch loads and output stores stay in flight across barriers. NT stores
// for out (write-once) to preserve L2 for prop/weights.

#define N_EDGES 320000
#define DI 128
#define DH 256
#define DO 128
#define TM 64                    // edges per tile
#define NT_TILES (N_EDGES / TM)  // 5000 tiles
#define PERSIST_GRID 512         // 2 blocks/CU x 256 CUs

typedef _Float16 half8v __attribute__((ext_vector_type(8)));
typedef _Float16 half4v __attribute__((ext_vector_type(4)));
typedef float floatx16 __attribute__((ext_vector_type(16)));

__device__ __forceinline__ float fast_tanh(float x) {
    float ax = __builtin_fabsf(x);
    float e = __expf(2.0f * ax);                       // v_mul + v_exp_f32
    float t = 1.0f - 2.0f * __builtin_amdgcn_rcpf(e + 1.0f);
    return __builtin_copysignf(t, x);
}

// Raw barrier: drain LDS ops only (ds_write visibility), keep global loads
// and stores in flight across the barrier (counted-vmcnt discipline, T4).
#define BAR() do { asm volatile("s_waitcnt lgkmcnt(0)" ::: "memory"); \
                   __builtin_amdgcn_s_barrier();                      \
                   asm volatile("" ::: "memory"); } while (0)

// ---------------------------------------------------------------------------
// Prologue: transpose+convert W1[128][256] -> W1T fp16 [256][128],
//                             W2[256][128] -> W2T fp16 [128][256]
// ---------------------------------------------------------------------------
__global__ __launch_bounds__(256) void wconvert(
    const float* __restrict__ W1, const float* __restrict__ W2,
    _Float16* __restrict__ W1T, _Float16* __restrict__ W2T)
{
    __shared__ float sT[32][33];
    int b = blockIdx.x;
    const float* src; _Float16* dst; int R, C, r0, c0;
    if (b < 32) { src = W1; dst = W1T; R = DI;  C = DH; r0 = (b & 3) * 32;  c0 = (b >> 2) * 32; }
    else { b -= 32; src = W2; dst = W2T; R = DH; C = DO; r0 = (b & 7) * 32; c0 = (b >> 3) * 32; }

    const int tid = threadIdx.x;
    const int cc = tid & 31, rr = tid >> 5;
    #pragma unroll
    for (int p = 0; p < 4; ++p) {
        int r = rr + p * 8;
        sT[r][cc] = src[(size_t)(r0 + r) * C + c0 + cc];
    }
    __syncthreads();
    #pragma unroll
    for (int p = 0; p < 4; ++p) {
        int c = rr + p * 8;                 // dst row = src col
        dst[(size_t)(c0 + c) * R + r0 + cc] = (_Float16)sT[cc][c];
    }
}

// ---------------------------------------------------------------------------
// Main fused persistent kernel. Per grid-stride iteration (tile t):
//   [idx + basis loads for t+G] -> GEMM1(sA[cur]) -> [issue prop gathers]
//   -> tanh -> sH -> BAR -> GEMM2(sH) -> [commit sA[cur^1]] -> store -> BAR
// mfma_f32_32x32x16_f16: A lane l: m=l&31, k=(l>>5)*8+j (contig 8)
//                        B lane l: n=l&31, k=(l>>5)*8+j (contig 8 in W^T)
//                        C/D lane l reg r: col=l&31, row=(r&3)+8*(r>>2)+4*(l>>5)
// ---------------------------------------------------------------------------
__global__ __launch_bounds__(256, 2) void pilayer_main(
    const int* __restrict__ idx_i, const int* __restrict__ idx_j,
    const float* __restrict__ prop, const float* __restrict__ basis,
    const _Float16* __restrict__ W1T, const float* __restrict__ b1,
    const _Float16* __restrict__ W2T, const float* __restrict__ b2,
    float* __restrict__ out)
{
    // stride pads: +8 fp16 keeps rows 16B-aligned, conflict-free b128 reads
    __shared__ _Float16 sA[2][TM][DI + 8];  // 2 x 17408 B
    __shared__ _Float16 sH[TM][DH + 8];     // 33792 B   (total 68608 B -> 2 blk/CU)

    const int tid = threadIdx.x;
    const int w   = tid >> 6;       // wave 0..3
    const int l   = tid & 63;
    const int lm  = l & 31;         // m / n within 32x32 tile
    const int lk  = (l >> 5) * 8;   // k sub-offset
    const int rowq = 4 * (l >> 5);  // row quad base for C/D layout
    const int c4  = (tid & 31) * 4; // staging col
    const int r0  = tid >> 5;       // staging row 0..7

    int t = blockIdx.x;

    // ---- prologue: stage tile t into sA[0] ----
    {
        #pragma unroll
        for (int p = 0; p < 8; ++p) {
            const int r = r0 + p * 8;
            const int e = t * TM + r;
            const int ii = idx_i[e], jj = idx_j[e];
            const float4 a  = *(const float4*)(prop  + (size_t)ii * DI + c4);
            const float4 bv = *(const float4*)(prop  + (size_t)jj * DI + c4);
            const float4 c  = *(const float4*)(basis + (size_t)e  * DI + c4);
            half4v hv;
            hv[0] = (_Float16)(a.x + bv.x + c.x);
            hv[1] = (_Float16)(a.y + bv.y + c.y);
            hv[2] = (_Float16)(a.z + bv.z + c.z);
            hv[3] = (_Float16)(a.w + bv.w + c.w);
            *(half4v*)(&sA[0][r][c4]) = hv;
        }
    }
    BAR();

    int cur = 0;
    for (; t < NT_TILES; t += PERSIST_GRID) {
        const int tn = t + PERSIST_GRID;
        const bool pf = (tn < NT_TILES);   // block-uniform

        // ---- idx + basis loads for next tile (cover: GEMM1 .. GEMM2) ----
        int ii[8], jj[8];
        float4 gc[8];
        if (pf) {
            #pragma unroll
            for (int p = 0; p < 8; ++p) {
                const int e = tn * TM + r0 + p * 8;
                ii[p] = idx_i[e];
                jj[p] = idx_j[e];
                gc[p] = *(const float4*)(basis + (size_t)e * DI + c4);
            }
        }

        // ---- GEMM1: h[64 x 256], wave w owns cols [w*64, w*64+64) ----
        floatx16 hacc[2][2] = {};
        {
            const _Float16* w1p = W1T + (size_t)(w * 64 + lm) * DI + lk;
            __builtin_amdgcn_s_setprio(1);
            #pragma unroll 4
            for (int kt = 0; kt < 8; ++kt) {
                const int ko = kt * 16;
                half8v a0  = *(const half8v*)(&sA[cur][lm][ko + lk]);
                half8v a1  = *(const half8v*)(&sA[cur][32 + lm][ko + lk]);
                half8v b0  = *(const half8v*)(w1p + ko);
                half8v b1f = *(const half8v*)(w1p + 32 * DI + ko);
                hacc[0][0] = __builtin_amdgcn_mfma_f32_32x32x16_f16(a0, b0,  hacc[0][0], 0, 0, 0);
                hacc[1][0] = __builtin_amdgcn_mfma_f32_32x32x16_f16(a1, b0,  hacc[1][0], 0, 0, 0);
                hacc[0][1] = __builtin_amdgcn_mfma_f32_32x32x16_f16(a0, b1f, hacc[0][1], 0, 0, 0);
                hacc[1][1] = __builtin_amdgcn_mfma_f32_32x32x16_f16(a1, b1f, hacc[1][1], 0, 0, 0);
            }
            __builtin_amdgcn_s_setprio(0);
        }

        // ---- idx-dependent prop gathers (cover: tanh + GEMM2) ----
        float4 ga[8], gb[8];
        if (pf) {
            #pragma unroll
            for (int p = 0; p < 8; ++p) {
                ga[p] = *(const float4*)(prop + (size_t)ii[p] * DI + c4);
                gb[p] = *(const float4*)(prop + (size_t)jj[p] * DI + c4);
            }
        }

        // ---- bias + tanh, write h to sH (C-layout -> memory layout) ----
        {
            const float bias0 = b1[w * 64 + lm];
            const float bias1 = b1[w * 64 + 32 + lm];
            #pragma unroll
            for (int mt = 0; mt < 2; ++mt) {
                #pragma unroll
                for (int r = 0; r < 16; ++r) {
                    const int row = mt * 32 + (r & 3) + 8 * (r >> 2) + rowq;
                    sH[row][w * 64 + lm]      = (_Float16)fast_tanh(hacc[mt][0][r] + bias0);
                    sH[row][w * 64 + 32 + lm] = (_Float16)fast_tanh(hacc[mt][1][r] + bias1);
                }
            }
        }
        BAR();

        // ---- GEMM2: out[64 x 128], wave w owns cols [w*32, w*32+32) ----
        floatx16 oacc[2] = {};
        {
            const _Float16* w2p = W2T + (size_t)(w * 32 + lm) * DH + lk;
            __builtin_amdgcn_s_setprio(1);
            #pragma unroll 4
            for (int kt = 0; kt < 16; ++kt) {
                const int ko = kt * 16;
                half8v a0 = *(const half8v*)(&sH[lm][ko + lk]);
                half8v a1 = *(const half8v*)(&sH[32 + lm][ko + lk]);
                half8v bb = *(const half8v*)(w2p + ko);
                oacc[0] = __builtin_amdgcn_mfma_f32_32x32x16_f16(a0, bb, oacc[0], 0, 0, 0);
                oacc[1] = __builtin_amdgcn_mfma_f32_32x32x16_f16(a1, bb, oacc[1], 0, 0, 0);
            }
            __builtin_amdgcn_s_setprio(0);
        }

        // ---- commit staging for next tile into sA[cur^1] ----
        if (pf) {
            #pragma unroll
            for (int p = 0; p < 8; ++p) {
                const int r = r0 + p * 8;
                half4v hv;
                hv[0] = (_Float16)(ga[p].x + gb[p].x + gc[p].x);
                hv[1] = (_Float16)(ga[p].y + gb[p].y + gc[p].y);
                hv[2] = (_Float16)(ga[p].z + gb[p].z + gc[p].z);
                hv[3] = (_Float16)(ga[p].w + gb[p].w + gc[p].w);
                *(half4v*)(&sA[cur ^ 1][r][c4]) = hv;
            }
        }

        // ---- epilogue: + b2, NT store fp32 (stays in flight past BAR) ----
        {
            const int col = w * 32 + lm;
            const float bias = b2[col];
            #pragma unroll
            for (int mt = 0; mt < 2; ++mt) {
                #pragma unroll
                for (int r = 0; r < 16; ++r) {
                    const int row = t * TM + mt * 32 + (r & 3) + 8 * (r >> 2) + rowq;
                    __builtin_nontemporal_store(oacc[mt][r] + bias,
                                                out + (size_t)row * DO + col);
                }
            }
        }

        BAR();
        cur ^= 1;
    }
}

extern "C" void kernel_launch(void* const* d_in, const int* in_sizes, int n_in,
                              void* d_out, int out_size, void* d_ws, size_t ws_size,
                              hipStream_t stream) {
    const int*   idx_i = (const int*)d_in[0];
    const int*   idx_j = (const int*)d_in[1];
    const float* prop  = (const float*)d_in[2];
    const float* basis = (const float*)d_in[3];
    const float* W1    = (const float*)d_in[4];
    const float* b1    = (const float*)d_in[5];
    const float* W2    = (const float*)d_in[6];
    const float* b2    = (const float*)d_in[7];
    float* out = (float*)d_out;

    _Float16* W1T = (_Float16*)d_ws;            // [256][128] = 64 KB
    _Float16* W2T = W1T + (size_t)DI * DH;      // [128][256] = 64 KB

    wconvert<<<64, 256, 0, stream>>>(W1, W2, W1T, W2T);
    pilayer_main<<<PERSIST_GRID, 256, 0, stream>>>(idx_i, idx_j, prop, basis,
                                                   W1T, b1, W2T, b2, out);
}